// Round 2
// baseline (319.337 us; speedup 1.0000x reference)
//
#include <hip/hip_runtime.h>
#include <math.h>

typedef __bf16 bf16x8 __attribute__((ext_vector_type(8)));
typedef __bf16 bf16x4 __attribute__((ext_vector_type(4)));
typedef float  f32x4  __attribute__((ext_vector_type(4)));
typedef short  s16x4  __attribute__((ext_vector_type(4)));

// Problem constants
constexpr int B_  = 128;
constexpr int M_  = 512;
constexpr int L_  = 1024;
constexpr int H_  = 64;
constexpr int KL_ = 1536;

// Tiling: 64 query rows x 64 key cols per tile; 4 waves = 2 row-halves (a) x 2 col-halves (c)
constexpr int BM  = 64;
constexpr int KT  = 64;
constexpr int NT  = 17;              // 17*64 = 1088 covers the 1024-band + 64-row skew
constexpr int KS  = 72;              // vt row stride (bf16): 144B
constexpr int PPS = 256;             // ppos row stride (bf16): 4 rolling 64-wide regions

// LDS layout — 51200 B total -> 3 blocks/CU at 160 KiB (was 79872 -> 2 blocks/CU)
constexpr int OFF_VT   = 0;          // vt[2][64][72] bf16   18432 B (double-buffered V^T)
constexpr int OFF_PPOS = 18432;      // ppos[64][256] bf16   32768 B (skewed storage: col = abs kcol & 255)
constexpr int SMEM_BYTES = 51200;
// epilogue overlays (after final barrier):
constexpr int OFF_OBUF = 0;          // [128][36] f32 partial O (18432 B, over vt)
constexpr int OFF_LSUM = 18432;      // [128] f32 row sums (over ppos)
constexpr int OBS = 36;

#define MFMA32(A, B, C) __builtin_amdgcn_mfma_f32_16x16x32_bf16((A), (B), (C), 0, 0, 0)

// PV MFMA: v_mfma_f32_16x16x16_bf16 (gfx950, cdna4_isa §10: A=2,B=2,C/D=4 regs).
// The legacy _1k builtin signature takes V4s (4 x short) operands -> bit_cast.
static __device__ __forceinline__ f32x4 mfma_pv(bf16x4 a, bf16x4 b, f32x4 c) {
  return __builtin_amdgcn_mfma_f32_16x16x16bf16_1k(
      __builtin_bit_cast(s16x4, a), __builtin_bit_cast(s16x4, b), c, 0, 0, 0);
}

__global__ __launch_bounds__(256, 3)
void seqattn_v6(const float* __restrict__ Q, const float* __restrict__ K,
                const float* __restrict__ V, const float* __restrict__ PE,
                float* __restrict__ O) {
  __shared__ alignas(16) char smem[SMEM_BYTES];
  __bf16* vtb  = (__bf16*)(smem + OFF_VT);
  __bf16* ppos = (__bf16*)(smem + OFF_PPOS);

  const int tid  = threadIdx.x;
  const int w    = tid >> 6;
  const int lane = tid & 63;
  const int nid  = lane & 15;
  const int qid  = lane >> 4;
  const int a    = w >> 1;            // rows 32a..32a+31
  const int c    = w & 1;             // tile cols 32c..32c+31
  const int b    = blockIdx.x;        // batch on x -> same-batch blocks share an XCD
  const int m0   = blockIdx.y * BM;
  const int swzn = (nid & 7) << 2;    // ppos bank swizzle (row&7 == nid&7 for all our rows)

  // ---- Q fragments (used as the MFMA *B* operand after the swap) ----
  // aq[it][f][j] = Q[m0+32a+16it+nid][8qid+j+32f]
  bf16x8 aq[2][2];
  #pragma unroll
  for (int it = 0; it < 2; ++it) {
    const float* qg = &Q[((size_t)b * M_ + m0 + 32 * a + 16 * it + nid) * H_];
    #pragma unroll
    for (int j = 0; j < 8; ++j) {
      aq[it][0][j] = (__bf16)qg[8 * qid + j];
      aq[it][1][j] = (__bf16)qg[32 + 8 * qid + j];
    }
  }

  f32x4 o[2][4];
  float lpart[2] = {0.f, 0.f};
  #pragma unroll
  for (int it = 0; it < 2; ++it)
    #pragma unroll
    for (int ht = 0; ht < 4; ++ht) o[it][ht] = (f32x4){0.f, 0.f, 0.f, 0.f};

  const int vj = (tid & 15) * 4, vh = (tid >> 4) * 4; // V staging: 4x4 reg transpose

  // PE A-frag gather base: pf[nt][f][j] = PE[(8qid+j+32f)*L + ch*64 + 32c + 16nt + nid]
  const float* peg = &PE[(size_t)(8 * qid) * L_ + 32 * c + nid];

  // ---------------- prologue ----------------
  // K tile 0 A-frags straight from global: ak[nt][f][j] = K[m0+32c+16nt+nid][8qid+j+32f]
  bf16x8 ak[2][2];
  #pragma unroll
  for (int nt = 0; nt < 2; ++nt) {
    const float* kg = &K[((size_t)b * KL_ + m0 + 32 * c + 16 * nt + nid) * H_ + 8 * qid];
    const f32x4 k0 = *(const f32x4*)kg;
    const f32x4 k1 = *(const f32x4*)(kg + 4);
    const f32x4 k2 = *(const f32x4*)(kg + 32);
    const f32x4 k3 = *(const f32x4*)(kg + 36);
    #pragma unroll
    for (int j = 0; j < 4; ++j) {
      ak[nt][0][j] = (__bf16)k0[j]; ak[nt][0][4 + j] = (__bf16)k1[j];
      ak[nt][1][j] = (__bf16)k2[j]; ak[nt][1][4 + j] = (__bf16)k3[j];
    }
  }
  // V tile 0
  f32x4 vr[4];
  {
    const float* vg = &V[((size_t)b * KL_ + m0 + vj) * H_ + vh];
    #pragma unroll
    for (int e = 0; e < 4; ++e) vr[e] = *(const f32x4*)(vg + e * H_);
  }
  // QPE chunk 0: Ppos^T = mfma(A=PE^T-frag, B=Q-frag); store skewed at col (l+row)&255
  {
    const f32x4 z = {0.f, 0.f, 0.f, 0.f};
    bf16x8 pf0[2][2];
    #pragma unroll
    for (int nt = 0; nt < 2; ++nt)
      #pragma unroll
      for (int j = 0; j < 8; ++j) {
        pf0[nt][0][j] = (__bf16)peg[(size_t)j * L_ + 16 * nt];
        pf0[nt][1][j] = (__bf16)peg[(size_t)(32 + j) * L_ + 16 * nt];
      }
    #pragma unroll
    for (int nt = 0; nt < 2; ++nt) {
      #pragma unroll
      for (int it = 0; it < 2; ++it) {
        f32x4 pp = MFMA32(pf0[nt][0], aq[it][0], z);
        pp = MFMA32(pf0[nt][1], aq[it][1], pp);
        const int row = 32 * a + 16 * it + nid;
        const int cb  = 32 * c + 16 * nt + 4 * qid + row;   // ch=0: l + row
        #pragma unroll
        for (int r = 0; r < 4; ++r)
          ppos[row * PPS + (((cb + r) & 255) ^ swzn)] = (__bf16)pp[r];
      }
    }
  }
  // stage V tile 0 -> buf 0
  #pragma unroll
  for (int e = 0; e < 4; ++e) {
    bf16x4 y = {(__bf16)vr[0][e], (__bf16)vr[1][e], (__bf16)vr[2][e], (__bf16)vr[3][e]};
    *(bf16x4*)&vtb[(vh + e) * KS + vj] = y;
  }
  __syncthreads();

  // ---------------- main loop: ONE barrier per tile ----------------
  for (int t = 0; t < NT; ++t) {
    // early ppos reads for this tile (aligned b64; address independent of QK)
    bf16x4 pe4[2][2];
    #pragma unroll
    for (int it = 0; it < 2; ++it) {
      const int row = 32 * a + 16 * it + nid;
      #pragma unroll
      for (int nt = 0; nt < 2; ++nt)
        pe4[it][nt] = *(const bf16x4*)
            &ppos[row * PPS + ((64 * (t & 3) + 32 * c + 16 * nt + 4 * qid) ^ swzn)];
    }

    // prefetch K/V tile t+1 into registers
    bf16x8 akn[2][2];
    if (t < 16) {
      const int j1 = m0 + KT * (t + 1);
      #pragma unroll
      for (int nt = 0; nt < 2; ++nt) {
        const float* kg = &K[((size_t)b * KL_ + j1 + 32 * c + 16 * nt + nid) * H_ + 8 * qid];
        const f32x4 k0 = *(const f32x4*)kg;
        const f32x4 k1 = *(const f32x4*)(kg + 4);
        const f32x4 k2 = *(const f32x4*)(kg + 32);
        const f32x4 k3 = *(const f32x4*)(kg + 36);
        #pragma unroll
        for (int j = 0; j < 4; ++j) {
          akn[nt][0][j] = (__bf16)k0[j]; akn[nt][0][4 + j] = (__bf16)k1[j];
          akn[nt][1][j] = (__bf16)k2[j]; akn[nt][1][4 + j] = (__bf16)k3[j];
        }
      }
      const float* vg = &V[((size_t)b * KL_ + j1 + vj) * H_ + vh];
      #pragma unroll
      for (int e = 0; e < 4; ++e) vr[e] = *(const f32x4*)(vg + e * H_);
    }
    // prefetch PE A-frags for chunk t+1 (PE is L2-resident)
    bf16x8 pf[2][2];
    if (t < 15) {
      const float* pc = peg + (t + 1) * 64;
      #pragma unroll
      for (int nt = 0; nt < 2; ++nt)
        #pragma unroll
        for (int j = 0; j < 8; ++j) {
          pf[nt][0][j] = (__bf16)pc[(size_t)j * L_ + 16 * nt];
          pf[nt][1][j] = (__bf16)pc[(size_t)(32 + j) * L_ + 16 * nt];
        }
    }

    const __bf16* vtt = vtb + (t & 1) * 64 * KS;
    const f32x4 z = {0.f, 0.f, 0.f, 0.f};

    // ---- QK^T swapped: S^T = mfma(A=K, B=Q). lane(nid,qid) reg r ->
    //      S[qrow=32a+16it+nid][kcol=64t+32c+16nt+4qid+r]  (registers only, no LDS)
    f32x4 s[2][2];
    #pragma unroll
    for (int nt = 0; nt < 2; ++nt)
      #pragma unroll
      for (int it = 0; it < 2; ++it) {
        s[it][nt] = MFMA32(ak[nt][0], aq[it][0], z);
        s[it][nt] = MFMA32(ak[nt][1], aq[it][1], s[it][nt]);
      }

    // ---- QPE chunk t+1 -> skewed store (visible after this tile's barrier) ----
    if (t < 15) {
      const int chb = 64 * ((t + 1) & 3);
      #pragma unroll
      for (int nt = 0; nt < 2; ++nt) {
        #pragma unroll
        for (int it = 0; it < 2; ++it) {
          f32x4 pp = MFMA32(pf[nt][0], aq[it][0], z);
          pp = MFMA32(pf[nt][1], aq[it][1], pp);
          const int row = 32 * a + 16 * it + nid;
          const int cb  = chb + 32 * c + 16 * nt + 4 * qid + row;
          #pragma unroll
          for (int r = 0; r < 4; ++r)
            ppos[row * PPS + (((cb + r) & 255) ^ swzn)] = (__bf16)pp[r];
        }
      }
    }

    // ---- softmax: exp in-register, build PV A-frags directly (no ps round-trip) ----
    const bool edge = (t == 0) || (t == 16);
    bf16x4 pa[2][2];
    #pragma unroll
    for (int it = 0; it < 2; ++it) {
      const int row = 32 * a + 16 * it + nid;
      #pragma unroll
      for (int nt = 0; nt < 2; ++nt) {
        const int lb = KT * t + 32 * c + 16 * nt + 4 * qid - row;
        #pragma unroll
        for (int r = 0; r < 4; ++r) {
          const int l = lb + r;
          float p;
          if (!edge || (unsigned)l < 1024u)
            p = __expf((s[it][nt][r] + (float)pe4[it][nt][r]) * 0.125f);
          else
            p = 0.f;
          lpart[it] += p;
          pa[it][nt][r] = (__bf16)p;
        }
      }
    }

    // ---- PV: 16x16x16, A = pa (registers), B = V^T from LDS ----
    #pragma unroll
    for (int nt = 0; nt < 2; ++nt) {
      bf16x4 vb[4];
      #pragma unroll
      for (int ht = 0; ht < 4; ++ht)
        vb[ht] = *(const bf16x4*)&vtt[(16 * ht + nid) * KS + 32 * c + 16 * nt + 4 * qid];
      #pragma unroll
      for (int it = 0; it < 2; ++it)
        #pragma unroll
        for (int ht = 0; ht < 4; ++ht)
          o[it][ht] = mfma_pv(pa[it][nt], vb[ht], o[it][ht]);
    }

    // ---- stage prefetched V tile t+1 into the other buffer; rotate K frags ----
    if (t < 16) {
      __bf16* vtn = vtb + ((t + 1) & 1) * 64 * KS;
      #pragma unroll
      for (int e = 0; e < 4; ++e) {
        bf16x4 y = {(__bf16)vr[0][e], (__bf16)vr[1][e], (__bf16)vr[2][e], (__bf16)vr[3][e]};
        *(bf16x4*)&vtn[(vh + e) * KS + vj] = y;
      }
      #pragma unroll
      for (int nt = 0; nt < 2; ++nt) {
        ak[nt][0] = akn[nt][0];
        ak[nt][1] = akn[nt][1];
      }
    }
    __syncthreads();
  }

  // ---------------- epilogue: merge c-halves, normalize, store ----------------
  float* lsum = (float*)(smem + OFF_LSUM);
  float* obuf = (float*)(smem + OFF_OBUF);

  #pragma unroll
  for (int it = 0; it < 2; ++it) {
    float v = lpart[it];
    v += __shfl_xor(v, 16);
    v += __shfl_xor(v, 32);
    lpart[it] = v;
  }
  if (qid == 0) {
    #pragma unroll
    for (int it = 0; it < 2; ++it)
      lsum[c * 64 + 32 * a + 16 * it + nid] = lpart[it];
  }
  if (c == 1) {
    #pragma unroll
    for (int it = 0; it < 2; ++it)
      #pragma unroll
      for (int ht = 0; ht < 4; ++ht)
        *(f32x4*)&obuf[(a * 64 + 16 * ht + nid) * OBS + 16 * it + 4 * qid] = o[it][ht];
  }
  __syncthreads();
  if (c == 0) {
    float inv[2][4];
    #pragma unroll
    for (int it = 0; it < 2; ++it)
      #pragma unroll
      for (int r = 0; r < 4; ++r) {
        const int row = 32 * a + 16 * it + 4 * qid + r;
        inv[it][r] = 1.f / (lsum[row] + lsum[64 + row]);
      }
    #pragma unroll
    for (int it = 0; it < 2; ++it) {
      #pragma unroll
      for (int ht = 0; ht < 4; ++ht) {
        f32x4 oo = o[it][ht] +
                   *(const f32x4*)&obuf[(a * 64 + 16 * ht + nid) * OBS + 16 * it + 4 * qid];
        #pragma unroll
        for (int r = 0; r < 4; ++r) {
          const int row = 32 * a + 16 * it + 4 * qid + r;
          O[((size_t)b * M_ + m0 + row) * H_ + 16 * ht + nid] = oo[r] * inv[it][r];
        }
      }
    }
  }
}

extern "C" void kernel_launch(void* const* d_in, const int* in_sizes, int n_in,
                              void* d_out, int out_size, void* d_ws, size_t ws_size,
                              hipStream_t stream) {
  const float* Q  = (const float*)d_in[0];   // B x M x H
  const float* K  = (const float*)d_in[1];   // B x (M+L) x H
  const float* V  = (const float*)d_in[2];   // B x (M+L) x H
  const float* PE = (const float*)d_in[3];   // 1 x H x L
  float* O = (float*)d_out;                  // B x M x H

  dim3 grid(B_, M_ / BM);                    // batch on x: XCD-local K/V reuse
  hipLaunchKernelGGL(seqattn_v6, grid, dim3(256), 0, stream, Q, K, V, PE, O);
}

// Round 3
// 250.657 us; speedup vs baseline: 1.2740x; 1.2740x over previous
//
#include <hip/hip_runtime.h>
#include <math.h>

typedef __bf16 bf16x8 __attribute__((ext_vector_type(8)));
typedef __bf16 bf16x4 __attribute__((ext_vector_type(4)));
typedef float  f32x4  __attribute__((ext_vector_type(4)));
typedef short  s16x4  __attribute__((ext_vector_type(4)));

// Problem constants
constexpr int B_  = 128;
constexpr int M_  = 512;
constexpr int L_  = 1024;
constexpr int H_  = 64;
constexpr int KL_ = 1536;

// Tiling: 64 query rows x 64 key cols per tile; 4 waves = 2 row-halves (a) x 2 col-halves (c)
constexpr int BM  = 64;
constexpr int KT  = 64;
constexpr int NT  = 17;              // 17*64 = 1088 covers the 1024-band + 64-row skew
constexpr int KS  = 72;              // vt row stride (bf16): 144B
constexpr int PPS = 272;             // ppos row stride (bf16): 544B = 136 dwords === 8 mod 32
                                     // -> pe4 b64 reads hit all 32 banks exactly 4x (balanced, free)

// LDS layout — 53248 B total -> 3 blocks/CU at 160 KiB
constexpr int OFF_VT   = 0;          // vt[2][64][72] bf16   18432 B (double-buffered V^T)
constexpr int OFF_PPOS = 18432;      // ppos[64][272] bf16   34816 B (skewed: col = abs kcol & 255)
constexpr int SMEM_BYTES = 53248;
// epilogue overlays (after final barrier):
constexpr int OFF_OBUF = 0;          // [128][36] f32 partial O (18432 B, over vt)
constexpr int OFF_LSUM = 18432;      // [128] f32 row sums (over ppos)
constexpr int OBS = 36;

#define MFMA32(A, B, C) __builtin_amdgcn_mfma_f32_16x16x32_bf16((A), (B), (C), 0, 0, 0)

// PV MFMA: v_mfma_f32_16x16x16_bf16 (gfx950). Legacy _1k builtin takes V4s -> bit_cast.
static __device__ __forceinline__ f32x4 mfma_pv(bf16x4 a, bf16x4 b, f32x4 c) {
  return __builtin_amdgcn_mfma_f32_16x16x16bf16_1k(
      __builtin_bit_cast(s16x4, a), __builtin_bit_cast(s16x4, b), c, 0, 0, 0);
}

// exp((s+pe)/8) = exp2((s+pe) * 0.125*log2(e))
constexpr float EXP2_SCALE = 0.18033688011112042f;

__global__ __launch_bounds__(256, 2)
void seqattn_v7(const float* __restrict__ Q, const float* __restrict__ K,
                const float* __restrict__ V, const float* __restrict__ PE,
                float* __restrict__ O) {
  __shared__ alignas(16) char smem[SMEM_BYTES];
  __bf16* vtb  = (__bf16*)(smem + OFF_VT);
  __bf16* ppos = (__bf16*)(smem + OFF_PPOS);

  const int tid  = threadIdx.x;
  const int w    = tid >> 6;
  const int lane = tid & 63;
  const int nid  = lane & 15;
  const int qid  = lane >> 4;
  const int a    = w >> 1;            // rows 32a..32a+31
  const int c    = w & 1;             // tile cols 32c..32c+31
  const int b    = blockIdx.x;        // batch on x -> same-batch blocks share an XCD
  const int m0   = blockIdx.y * BM;

  // ---- Q fragments (MFMA *B* operand after the operand swap) ----
  // aq[it][f][j] = Q[m0+32a+16it+nid][8qid+j+32f]
  bf16x8 aq[2][2];
  #pragma unroll
  for (int it = 0; it < 2; ++it) {
    const float* qg = &Q[((size_t)b * M_ + m0 + 32 * a + 16 * it + nid) * H_];
    #pragma unroll
    for (int j = 0; j < 8; ++j) {
      aq[it][0][j] = (__bf16)qg[8 * qid + j];
      aq[it][1][j] = (__bf16)qg[32 + 8 * qid + j];
    }
  }

  f32x4 o[2][4];
  float lpart[2] = {0.f, 0.f};
  #pragma unroll
  for (int it = 0; it < 2; ++it)
    #pragma unroll
    for (int ht = 0; ht < 4; ++ht) o[it][ht] = (f32x4){0.f, 0.f, 0.f, 0.f};

  const int vj = (tid & 15) * 4, vh = (tid >> 4) * 4; // V staging: 4x4 reg transpose

  // PE gather base: frag[nt][f][j] = PE[(8qid+j+32f)*L + ch*64 + 32c + 16nt + nid]
  const float* peg = &PE[(size_t)(8 * qid) * L_ + 32 * c + nid];

  // ---------------- prologue ----------------
  // K tile 0 A-frags straight from global: ak[nt][f][j] = K[m0+32c+16nt+nid][8qid+j+32f]
  bf16x8 ak[2][2];
  #pragma unroll
  for (int nt = 0; nt < 2; ++nt) {
    const float* kg = &K[((size_t)b * KL_ + m0 + 32 * c + 16 * nt + nid) * H_ + 8 * qid];
    const f32x4 k0 = *(const f32x4*)kg;
    const f32x4 k1 = *(const f32x4*)(kg + 4);
    const f32x4 k2 = *(const f32x4*)(kg + 32);
    const f32x4 k3 = *(const f32x4*)(kg + 36);
    #pragma unroll
    for (int j = 0; j < 4; ++j) {
      ak[nt][0][j] = (__bf16)k0[j]; ak[nt][0][4 + j] = (__bf16)k1[j];
      ak[nt][1][j] = (__bf16)k2[j]; ak[nt][1][4 + j] = (__bf16)k3[j];
    }
  }
  // V tile 0
  f32x4 vr[4];
  {
    const float* vg = &V[((size_t)b * KL_ + m0 + vj) * H_ + vh];
    #pragma unroll
    for (int e = 0; e < 4; ++e) vr[e] = *(const f32x4*)(vg + e * H_);
  }
  // QPE chunk 0: Ppos^T = mfma(A=PE^T-frag, B=Q-frag); store skewed at col (l+row)&255
  {
    const f32x4 z = {0.f, 0.f, 0.f, 0.f};
    #pragma unroll
    for (int nt = 0; nt < 2; ++nt) {
      bf16x8 pf0, pf1;
      #pragma unroll
      for (int j = 0; j < 8; ++j) {
        pf0[j] = (__bf16)peg[(size_t)j * L_ + 16 * nt];
        pf1[j] = (__bf16)peg[(size_t)(32 + j) * L_ + 16 * nt];
      }
      #pragma unroll
      for (int it = 0; it < 2; ++it) {
        f32x4 pp = MFMA32(pf0, aq[it][0], z);
        pp = MFMA32(pf1, aq[it][1], pp);
        const int row = 32 * a + 16 * it + nid;
        const int cb  = 32 * c + 16 * nt + 4 * qid + row;   // ch=0: l + row
        #pragma unroll
        for (int r = 0; r < 4; ++r)
          ppos[row * PPS + ((cb + r) & 255)] = (__bf16)pp[r];
      }
    }
  }
  // stage V tile 0 -> buf 0
  #pragma unroll
  for (int e = 0; e < 4; ++e) {
    bf16x4 y = {(__bf16)vr[0][e], (__bf16)vr[1][e], (__bf16)vr[2][e], (__bf16)vr[3][e]};
    *(bf16x4*)&vtb[(vh + e) * KS + vj] = y;
  }
  __syncthreads();

  // ---------------- main loop: ONE barrier per tile ----------------
  for (int t = 0; t < NT; ++t) {
    // early ppos reads for this tile (aligned b64; balanced across banks)
    bf16x4 pe4[2][2];
    #pragma unroll
    for (int it = 0; it < 2; ++it) {
      const int row = 32 * a + 16 * it + nid;
      #pragma unroll
      for (int nt = 0; nt < 2; ++nt)
        pe4[it][nt] = *(const bf16x4*)
            &ppos[row * PPS + 64 * (t & 3) + 32 * c + 16 * nt + 4 * qid];
    }

    // prefetch K/V tile t+1 into registers (K is the HBM-latency stream)
    bf16x8 akn[2][2];
    if (t < 16) {
      const int j1 = m0 + KT * (t + 1);
      #pragma unroll
      for (int nt = 0; nt < 2; ++nt) {
        const float* kg = &K[((size_t)b * KL_ + j1 + 32 * c + 16 * nt + nid) * H_ + 8 * qid];
        const f32x4 k0 = *(const f32x4*)kg;
        const f32x4 k1 = *(const f32x4*)(kg + 4);
        const f32x4 k2 = *(const f32x4*)(kg + 32);
        const f32x4 k3 = *(const f32x4*)(kg + 36);
        #pragma unroll
        for (int j = 0; j < 4; ++j) {
          akn[nt][0][j] = (__bf16)k0[j]; akn[nt][0][4 + j] = (__bf16)k1[j];
          akn[nt][1][j] = (__bf16)k2[j]; akn[nt][1][4 + j] = (__bf16)k3[j];
        }
      }
      const float* vg = &V[((size_t)b * KL_ + j1 + vj) * H_ + vh];
      #pragma unroll
      for (int e = 0; e < 4; ++e) vr[e] = *(const f32x4*)(vg + e * H_);
    }

    const __bf16* vtt = vtb + (t & 1) * 64 * KS;
    const f32x4 z = {0.f, 0.f, 0.f, 0.f};

    // ---- QK^T swapped: S^T = mfma(A=K, B=Q). lane(nid,qid) reg r ->
    //      S[qrow=32a+16it+nid][kcol=64t+32c+16nt+4qid+r]  (registers only, no LDS)
    f32x4 s[2][2];
    #pragma unroll
    for (int nt = 0; nt < 2; ++nt)
      #pragma unroll
      for (int it = 0; it < 2; ++it) {
        s[it][nt] = MFMA32(ak[nt][0], aq[it][0], z);
        s[it][nt] = MFMA32(ak[nt][1], aq[it][1], s[it][nt]);
      }

    // ---- QPE chunk t+1: gather PE frags (transient) + MFMA -> skewed store ----
    if (t < 15) {
      const int chb = 64 * ((t + 1) & 3);
      const float* pc = peg + (t + 1) * 64;
      #pragma unroll
      for (int nt = 0; nt < 2; ++nt) {
        bf16x8 pf0, pf1;
        #pragma unroll
        for (int j = 0; j < 8; ++j) {
          pf0[j] = (__bf16)pc[(size_t)j * L_ + 16 * nt];
          pf1[j] = (__bf16)pc[(size_t)(32 + j) * L_ + 16 * nt];
        }
        #pragma unroll
        for (int it = 0; it < 2; ++it) {
          f32x4 pp = MFMA32(pf0, aq[it][0], z);
          pp = MFMA32(pf1, aq[it][1], pp);
          const int row = 32 * a + 16 * it + nid;
          const int cb  = chb + 32 * c + 16 * nt + 4 * qid + row;
          #pragma unroll
          for (int r = 0; r < 4; ++r)
            ppos[row * PPS + ((cb + r) & 255)] = (__bf16)pp[r];
        }
      }
    }

    // ---- softmax: exp in-register, build PV A-frags directly ----
    const bool edge = (t == 0) || (t == 16);
    bf16x4 pa[2][2];
    #pragma unroll
    for (int it = 0; it < 2; ++it) {
      const int row = 32 * a + 16 * it + nid;
      #pragma unroll
      for (int nt = 0; nt < 2; ++nt) {
        const int lb = KT * t + 32 * c + 16 * nt + 4 * qid - row;
        #pragma unroll
        for (int r = 0; r < 4; ++r) {
          const int l = lb + r;
          float p;
          if (!edge || (unsigned)l < 1024u)
            p = exp2f((s[it][nt][r] + (float)pe4[it][nt][r]) * EXP2_SCALE);
          else
            p = 0.f;
          lpart[it] += p;
          pa[it][nt][r] = (__bf16)p;
        }
      }
    }

    // ---- PV: 16x16x16, A = pa (registers), B = V^T from LDS ----
    #pragma unroll
    for (int nt = 0; nt < 2; ++nt) {
      bf16x4 vb[4];
      #pragma unroll
      for (int ht = 0; ht < 4; ++ht)
        vb[ht] = *(const bf16x4*)&vtt[(16 * ht + nid) * KS + 32 * c + 16 * nt + 4 * qid];
      #pragma unroll
      for (int it = 0; it < 2; ++it)
        #pragma unroll
        for (int ht = 0; ht < 4; ++ht)
          o[it][ht] = mfma_pv(pa[it][nt], vb[ht], o[it][ht]);
    }

    // ---- stage prefetched V tile t+1 into the other buffer; rotate K frags ----
    if (t < 16) {
      __bf16* vtn = vtb + ((t + 1) & 1) * 64 * KS;
      #pragma unroll
      for (int e = 0; e < 4; ++e) {
        bf16x4 y = {(__bf16)vr[0][e], (__bf16)vr[1][e], (__bf16)vr[2][e], (__bf16)vr[3][e]};
        *(bf16x4*)&vtn[(vh + e) * KS + vj] = y;
      }
      #pragma unroll
      for (int nt = 0; nt < 2; ++nt) {
        ak[nt][0] = akn[nt][0];
        ak[nt][1] = akn[nt][1];
      }
    }
    __syncthreads();
  }

  // ---------------- epilogue: merge c-halves, normalize, store ----------------
  float* lsum = (float*)(smem + OFF_LSUM);
  float* obuf = (float*)(smem + OFF_OBUF);

  #pragma unroll
  for (int it = 0; it < 2; ++it) {
    float v = lpart[it];
    v += __shfl_xor(v, 16);
    v += __shfl_xor(v, 32);
    lpart[it] = v;
  }
  if (qid == 0) {
    #pragma unroll
    for (int it = 0; it < 2; ++it)
      lsum[c * 64 + 32 * a + 16 * it + nid] = lpart[it];
  }
  if (c == 1) {
    #pragma unroll
    for (int it = 0; it < 2; ++it)
      #pragma unroll
      for (int ht = 0; ht < 4; ++ht)
        *(f32x4*)&obuf[(a * 64 + 16 * ht + nid) * OBS + 16 * it + 4 * qid] = o[it][ht];
  }
  __syncthreads();
  if (c == 0) {
    float inv[2][4];
    #pragma unroll
    for (int it = 0; it < 2; ++it)
      #pragma unroll
      for (int r = 0; r < 4; ++r) {
        const int row = 32 * a + 16 * it + 4 * qid + r;
        inv[it][r] = 1.f / (lsum[row] + lsum[64 + row]);
      }
    #pragma unroll
    for (int it = 0; it < 2; ++it) {
      #pragma unroll
      for (int ht = 0; ht < 4; ++ht) {
        f32x4 oo = o[it][ht] +
                   *(const f32x4*)&obuf[(a * 64 + 16 * ht + nid) * OBS + 16 * it + 4 * qid];
        #pragma unroll
        for (int r = 0; r < 4; ++r) {
          const int row = 32 * a + 16 * it + 4 * qid + r;
          O[((size_t)b * M_ + m0 + row) * H_ + 16 * ht + nid] = oo[r] * inv[it][r];
        }
      }
    }
  }
}

extern "C" void kernel_launch(void* const* d_in, const int* in_sizes, int n_in,
                              void* d_out, int out_size, void* d_ws, size_t ws_size,
                              hipStream_t stream) {
  const float* Q  = (const float*)d_in[0];   // B x M x H
  const float* K  = (const float*)d_in[1];   // B x (M+L) x H
  const float* V  = (const float*)d_in[2];   // B x (M+L) x H
  const float* PE = (const float*)d_in[3];   // 1 x H x L
  float* O = (float*)d_out;                  // B x M x H

  dim3 grid(B_, M_ / BM);                    // batch on x: XCD-local K/V reuse
  hipLaunchKernelGGL(seqattn_v7, grid, dim3(256), 0, stream, Q, K, V, PE, O);
}